// Round 1
// baseline (564.388 us; speedup 1.0000x reference)
//
#include <hip/hip_runtime.h>
#include <hip/hip_bf16.h>

// Problem constants (fixed by setup_inputs):
//   B=1, T=16384 -> S=16384, C=1280, H=16, D=80, 3C=3840, block=16, nb=1024
// Inputs FP32, output FP32. Workspace budget 222,822,400 B (proven available
// in the previous session).
#define S_TOK   16384
#define C_DIM   1280
#define C3_DIM  3840
#define H_DIM   16
#define D_DIM   80
#define BLK     16

using u16x8  = __attribute__((ext_vector_type(8))) unsigned short;
using bf16x8 = __attribute__((ext_vector_type(8))) __bf16;
using f32x4  = __attribute__((ext_vector_type(4))) float;

__device__ __forceinline__ unsigned short f2bf(float f) {
    return __bfloat16_as_ushort(__float2bfloat16(f));
}
__device__ __forceinline__ float bf2f(unsigned short u) {
    unsigned int x = (unsigned int)u << 16;
    return __builtin_bit_cast(float, x);
}
// Async global->LDS, 16 B per lane. LDS dest is wave-uniform base + lane*16
// (m104/m108): destination must be linear; swizzle is applied on the GLOBAL
// source address and on the ds_read side (rule 21: both-sides-or-neither).
__device__ __forceinline__ void gload_lds16(const unsigned short* g, unsigned short* l) {
    __builtin_amdgcn_global_load_lds(
        (const __attribute__((address_space(1))) void*)g,
        (__attribute__((address_space(3))) void*)l, 16, 0, 0);
}

// ---------------------------------------------------------------------------
// One-shot weight prep: fp32 W[K][N] -> bf16 W^T[N][K], LDS-tiled.
// ---------------------------------------------------------------------------
__global__ __launch_bounds__(256) void transpose_cvt(
    const float* __restrict__ W, unsigned short* __restrict__ WT, int K, int N)
{
    __shared__ float tile[32][33];
    const int n0 = blockIdx.x * 32, k0 = blockIdx.y * 32;
    const int tx = threadIdx.x & 31, ty = threadIdx.x >> 5;   // 32x8
#pragma unroll
    for (int i = ty; i < 32; i += 8)
        tile[i][tx] = W[(size_t)(k0 + i) * N + n0 + tx];
    __syncthreads();
#pragma unroll
    for (int i = ty; i < 32; i += 8)
        WT[(size_t)(n0 + i) * K + k0 + tx] = f2bf(tile[tx][i]);
}

// ---------------------------------------------------------------------------
// Prepass: xg[s][:] = bf16(x[wi[s]][:]).
// Hoists the row-gather and fp32->bf16 convert OUT of GEMM1's staging so the
// GEMM can use global_load_lds direct (conversion can't ride the DMA path).
// 126 MB streamed => ~20 us; pays for itself by halving GEMM1 A staging bytes
// and removing all convert VALU + row_idx lookups from the hot loop.
// ---------------------------------------------------------------------------
__global__ __launch_bounds__(256) void gather_cvt(
    const float* __restrict__ x, const int* __restrict__ wi,
    unsigned short* __restrict__ xg)
{
    int idx = blockIdx.x * 256 + threadIdx.x;   // over S*160 (exact)
    int s  = idx / 160;
    int c8 = (idx - s * 160) * 8;
    const float* src = x + (size_t)wi[s] * C_DIM + c8;
    f32x4 v0 = *(const f32x4*)src;
    f32x4 v1 = *(const f32x4*)(src + 4);
    u16x8 o;
    o[0]=f2bf(v0[0]); o[1]=f2bf(v0[1]); o[2]=f2bf(v0[2]); o[3]=f2bf(v0[3]);
    o[4]=f2bf(v1[0]); o[5]=f2bf(v1[1]); o[6]=f2bf(v1[2]); o[7]=f2bf(v1[3]);
    *(u16x8*)&xg[(size_t)s * C_DIM + c8] = o;
}

// ---------------------------------------------------------------------------
// Tiled bf16 MFMA GEMM, global_load_lds staging + XOR-swizzled LDS.
//   A : [M][K] bf16.   B: bf16 [N][K] (PRE-TRANSPOSED).
//   C[m][n] = sum_k A[m][k] * BT[n][k];  out fp32 (OUTF32) or bf16.
// 128x128 tile, BK=64, 4 waves (2x2), each wave 64x64 via 4x4 16x16x32 MFMAs.
//
// LDS layout: flat [128 rows][64 k] bf16 (16 KB per tile, NO pad).
//   linear 16B chunk ch  <->  row r=ch>>3, swizzled col8 = (ch&7)^(r&7).
//   ds_read side: byte = (row<<7) + (colb ^ ((row&7)<<4)).
//   16 lanes of a quad (rows r..r+15, same colb) land on 8 distinct 16B slots
//   -> 2-way bank aliasing = free (m136). Replaces the old +8 pad, which was
//   incompatible with global_load_lds' linear wave-uniform destination.
// ---------------------------------------------------------------------------
#define TM 128
#define TN 128
#define BK 64

template<bool OUTF32>
__global__ __launch_bounds__(256) void gemm_mfma(
    const unsigned short* __restrict__ A,   // [M][K] bf16
    const unsigned short* __restrict__ BT,  // [N][K] bf16
    void* __restrict__ Cp,                  // [M][N] fp32 or bf16
    int N, int K)
{
    __shared__ __align__(16) unsigned short As[TM * BK];
    __shared__ __align__(16) unsigned short Bs[TN * BK];

    const int m0   = blockIdx.x * TM;
    const int n0   = blockIdx.y * TN;
    const int tid  = threadIdx.x;
    const int lane = tid & 63;
    const int wv   = tid >> 6;
    const int wm   = (wv >> 1) * 64;
    const int wn   = (wv & 1) * 64;
    const int lrow = lane & 15;
    const int quad = lane >> 4;

    // Per-lane staging descriptors: each wave issues 4 chunks-of-64-lanes per
    // tile; lane's chunk ch -> row, inverse-swizzled global col.
    int r_[4], csw[4];
#pragma unroll
    for (int c = 0; c < 4; c++) {
        int ch = (wv * 4 + c) * 64 + lane;
        r_[c]  = ch >> 3;                          // 0..127
        csw[c] = ((ch & 7) ^ (r_[c] & 7)) << 3;    // 0..56 (elements)
    }

    // Swizzled ds_read byte offsets per fragment row.
    int aoff[4], asw[4], boff[4], bsw[4];
#pragma unroll
    for (int t = 0; t < 4; t++) {
        int ra = wm + t * 16 + lrow;
        aoff[t] = ra << 7;  asw[t] = (ra & 7) << 4;
        int rb = wn + t * 16 + lrow;
        boff[t] = rb << 7;  bsw[t] = (rb & 7) << 4;
    }

    f32x4 acc[4][4];
#pragma unroll
    for (int i = 0; i < 4; i++)
#pragma unroll
        for (int j = 0; j < 4; j++)
            acc[i][j] = (f32x4){0.f, 0.f, 0.f, 0.f};

    for (int kt = 0; kt < K; kt += BK) {
#pragma unroll
        for (int c = 0; c < 4; c++)
            gload_lds16(A + (size_t)(m0 + r_[c]) * K + kt + csw[c],
                        As + (wv * 4 + c) * 512);
#pragma unroll
        for (int c = 0; c < 4; c++)
            gload_lds16(BT + (size_t)(n0 + r_[c]) * K + kt + csw[c],
                        Bs + (wv * 4 + c) * 512);
        __syncthreads();   // drains vmcnt -> staged data visible

#pragma unroll
        for (int ks = 0; ks < BK; ks += 32) {
            const int cb = (ks << 1) + (quad << 4);   // logical byte col
            bf16x8 af[4], bfr[4];
#pragma unroll
            for (int mt = 0; mt < 4; mt++)
                af[mt] = *(const bf16x8*)((const char*)As +
                                          aoff[mt] + (cb ^ asw[mt]));
#pragma unroll
            for (int nt = 0; nt < 4; nt++)
                bfr[nt] = *(const bf16x8*)((const char*)Bs +
                                           boff[nt] + (cb ^ bsw[nt]));
#pragma unroll
            for (int mt = 0; mt < 4; mt++)
#pragma unroll
                for (int nt = 0; nt < 4; nt++)
                    acc[mt][nt] = __builtin_amdgcn_mfma_f32_16x16x32_bf16(
                        af[mt], bfr[nt], acc[mt][nt], 0, 0, 0);
        }
        __syncthreads();
    }

    // epilogue: D row = quad*4 + r, col = lane&15  (HW-verified C/D layout)
#pragma unroll
    for (int mt = 0; mt < 4; mt++)
#pragma unroll
        for (int nt = 0; nt < 4; nt++)
#pragma unroll
            for (int r = 0; r < 4; r++) {
                int row = m0 + wm + mt * 16 + quad * 4 + r;
                int col = n0 + wn + nt * 16 + lrow;
                if (OUTF32)
                    ((float*)Cp)[(size_t)row * N + col] = acc[mt][nt][r];
                else
                    ((unsigned short*)Cp)[(size_t)row * N + col] =
                        f2bf(acc[mt][nt][r]);
            }
}

// ---------------------------------------------------------------------------
// RoPE-style mix (in place on bf16 qkv, windowed order), 8 elems/thread:
//   q' = q*cos[wi[s]] + k*sin[wi[s]];  k' = k*cos[wi[s]] - q*sin[wi[s]]
// ---------------------------------------------------------------------------
__global__ __launch_bounds__(256) void rope_kernel(
    unsigned short* __restrict__ qkv,
    const float* __restrict__ cosp,
    const float* __restrict__ sinp,
    const int* __restrict__ wi)
{
    int idx = blockIdx.x * 256 + threadIdx.x;   // over S*160 (exact)
    int s  = idx / 160;
    int ch = idx - s * 160;
    int c  = ch * 8;
    int d  = c % D_DIM;                          // 80 % 8 == 0: chunk stays in one d-period
    int src = wi[s];
    const float* cp = cosp + (size_t)src * D_DIM + d;
    const float* sp = sinp + (size_t)src * D_DIM + d;
    f32x4 c0 = *(const f32x4*)cp, c1 = *(const f32x4*)(cp + 4);
    f32x4 s0 = *(const f32x4*)sp, s1 = *(const f32x4*)(sp + 4);
    size_t base = (size_t)s * C3_DIM + c;
    u16x8 qv = *(const u16x8*)(qkv + base);
    u16x8 kv = *(const u16x8*)(qkv + base + C_DIM);
    u16x8 qo, ko;
#pragma unroll
    for (int j = 0; j < 8; j++) {
        float cw = (j < 4) ? c0[j] : c1[j - 4];
        float sw = (j < 4) ? s0[j] : s1[j - 4];
        float q = bf2f(qv[j]), k = bf2f(kv[j]);
        qo[j] = f2bf(q * cw + k * sw);
        ko[j] = f2bf(k * cw - q * sw);
    }
    *(u16x8*)(qkv + base)         = qo;
    *(u16x8*)(qkv + base + C_DIM) = ko;
}

// ---------------------------------------------------------------------------
// Block attention: one workgroup per (block b, head h).
// 16x16 scores over D=80, row softmax, 16x80 PV, fp32 in LDS.
// Staging vectorized to 16 B loads; LDS stride 81 (17j mod 32 covers all
// 16 banks -> conflict-free k-column reads; old stride 80 was 8-way).
// Row j scattered to un-permuted position wi[j].
// ---------------------------------------------------------------------------
__global__ __launch_bounds__(256) void attn_kernel(
    const unsigned short* __restrict__ qkv,
    unsigned short* __restrict__ y,
    const int* __restrict__ wi)
{
    const int b = blockIdx.x;
    const int h = blockIdx.y;
    __shared__ float qs[BLK][81], ks[BLK][81], vs[BLK][81];
    __shared__ float pr[BLK][17];
    __shared__ int   orow[BLK];
    const int tid = threadIdx.x;

    if (tid < BLK) orow[tid] = wi[b * BLK + tid];
    // 3 * 16 rows * 80 d = 3840 elems = 480 chunks of 8
    for (int ch = tid; ch < 480; ch += 256) {
        int which = ch / 160;                 // 0=q, 1=k, 2=v
        int rem = ch - which * 160;
        int r = rem / 10;
        int c8 = (rem - r * 10) * 8;
        const unsigned short* srcp = qkv +
            (size_t)(b * BLK + r) * C3_DIM + which * C_DIM + h * D_DIM + c8;
        u16x8 v = *(const u16x8*)srcp;
        float* dst = (which == 0) ? &qs[r][c8]
                   : (which == 1) ? &ks[r][c8] : &vs[r][c8];
#pragma unroll
        for (int j = 0; j < 8; j++) dst[j] = bf2f(v[j]);
    }
    __syncthreads();
    {
        int i = tid >> 4, j = tid & 15;
        float a = 0.f;
#pragma unroll
        for (int d = 0; d < D_DIM; d++) a += qs[i][d] * ks[j][d];
        pr[i][j] = a * 0.11180339887498948f;   // 1/sqrt(80)
    }
    __syncthreads();
    if (tid < BLK) {
        float m = -1e30f;
#pragma unroll
        for (int j = 0; j < BLK; j++) m = fmaxf(m, pr[tid][j]);
        float sum = 0.f;
        float e[BLK];
#pragma unroll
        for (int j = 0; j < BLK; j++) { e[j] = __expf(pr[tid][j] - m); sum += e[j]; }
        float inv = 1.f / sum;
#pragma unroll
        for (int j = 0; j < BLK; j++) pr[tid][j] = e[j] * inv;
    }
    __syncthreads();
    for (int i = tid; i < BLK * D_DIM; i += 256) {
        int r = i / D_DIM, d = i - r * D_DIM;
        float a = 0.f;
#pragma unroll
        for (int j = 0; j < BLK; j++) a += pr[r][j] * vs[j][d];
        y[(size_t)orow[r] * C_DIM + h * D_DIM + d] = f2bf(a);
    }
}

extern "C" void kernel_launch(void* const* d_in, const int* in_sizes, int n_in,
                              void* d_out, int out_size, void* d_ws, size_t ws_size,
                              hipStream_t stream)
{
    const float* x     = (const float*)d_in[0];
    const float* cosp  = (const float*)d_in[1];
    const float* sinp  = (const float*)d_in[2];
    const float* Wqkv  = (const float*)d_in[3];
    const float* Wproj = (const float*)d_in[4];
    const int*   wi    = (const int*)d_in[5];

    // workspace layout (bytes):
    //   qkv    @ 0          : S*3840*2    = 125,829,120
    //   yun    @ 125829120  : S*1280*2    =  41,943,040
    //   wqkvT  @ 167772160  : 3840*1280*2 =   9,830,400   (bf16 [N][K])
    //   wprojT @ 177602560  : 1280*1280*2 =   3,276,800   (bf16 [N][K])
    //   xg     @ 180879360  : S*1280*2    =  41,943,040   (bf16 gathered x)
    // total 222,822,400 B (== the 222.8 MB proven available).
    char* ws = (char*)d_ws;
    unsigned short* qkv    = (unsigned short*)ws;
    unsigned short* yun    = (unsigned short*)(ws + 125829120ull);
    unsigned short* wqkvT  = (unsigned short*)(ws + 167772160ull);
    unsigned short* wprojT = (unsigned short*)(ws + 177602560ull);
    unsigned short* xg     = (unsigned short*)(ws + 180879360ull);

    // 0) weight prep: fp32 [K][N] -> bf16 [N][K]
    transpose_cvt<<<dim3(C3_DIM / 32, C_DIM / 32), 256, 0, stream>>>(
        Wqkv, wqkvT, C_DIM, C3_DIM);
    transpose_cvt<<<dim3(C_DIM / 32, C_DIM / 32), 256, 0, stream>>>(
        Wproj, wprojT, C_DIM, C_DIM);

    // 0b) gather + cvt prepass: xg[s] = bf16(x[wi[s]])
    gather_cvt<<<S_TOK * 160 / 256, 256, 0, stream>>>(x, wi, xg);

    // 1) qkv = xg @ W_qkv   (bf16 out to workspace)
    gemm_mfma<false><<<dim3(S_TOK / TM, C3_DIM / TN), 256, 0, stream>>>(
        xg, wqkvT, qkv, C3_DIM, C_DIM);

    // 2) rope mix in place (windowed order)
    rope_kernel<<<S_TOK * 160 / 256, 256, 0, stream>>>(qkv, cosp, sinp, wi);

    // 3) block attention; scatter rows to un-permuted order
    attn_kernel<<<dim3(S_TOK / BLK, H_DIM), 256, 0, stream>>>(qkv, yun, wi);

    // 4) out = y @ W_proj -> fp32 d_out
    gemm_mfma<true><<<dim3(S_TOK / TM, C_DIM / TN), 256, 0, stream>>>(
        yun, wprojT, d_out, C_DIM, C_DIM);
}

// Round 2
// 500.961 us; speedup vs baseline: 1.1266x; 1.1266x over previous
//
#include <hip/hip_runtime.h>
#include <hip/hip_bf16.h>

// Problem constants (fixed by setup_inputs):
//   B=1, T=16384 -> S=16384, C=1280, H=16, D=80, 3C=3840, block=16, nb=1024
// Inputs FP32, output FP32. Workspace budget 222,822,400 B.
#define S_TOK   16384
#define C_DIM   1280
#define C3_DIM  3840
#define H_DIM   16
#define D_DIM   80
#define BLK     16

using u16x8  = __attribute__((ext_vector_type(8))) unsigned short;
using u16x4  = __attribute__((ext_vector_type(4))) unsigned short;
using bf16x8 = __attribute__((ext_vector_type(8))) __bf16;
using f32x4  = __attribute__((ext_vector_type(4))) float;

__device__ __forceinline__ unsigned short f2bf(float f) {
    return __bfloat16_as_ushort(__float2bfloat16(f));
}
__device__ __forceinline__ float bf2f(unsigned short u) {
    unsigned int x = (unsigned int)u << 16;
    return __builtin_bit_cast(float, x);
}
__device__ __forceinline__ void gload_lds16(const unsigned short* g, unsigned short* l) {
    __builtin_amdgcn_global_load_lds(
        (const __attribute__((address_space(1))) void*)g,
        (__attribute__((address_space(3))) void*)l, 16, 0, 0);
}

// ---------------------------------------------------------------------------
// One-shot weight prep: fp32 W[K][N] -> bf16 W^T[N][K], LDS-tiled.
// ---------------------------------------------------------------------------
__global__ __launch_bounds__(256) void transpose_cvt(
    const float* __restrict__ W, unsigned short* __restrict__ WT, int K, int N)
{
    __shared__ float tile[32][33];
    const int n0 = blockIdx.x * 32, k0 = blockIdx.y * 32;
    const int tx = threadIdx.x & 31, ty = threadIdx.x >> 5;   // 32x8
#pragma unroll
    for (int i = ty; i < 32; i += 8)
        tile[i][tx] = W[(size_t)(k0 + i) * N + n0 + tx];
    __syncthreads();
#pragma unroll
    for (int i = ty; i < 32; i += 8)
        WT[(size_t)(n0 + i) * K + k0 + tx] = f2bf(tile[tx][i]);
}

// ---------------------------------------------------------------------------
// Prepass: xg[s][:] = bf16(x[wi[s]][:]).  (enables global_load_lds in GEMM1)
// ---------------------------------------------------------------------------
__global__ __launch_bounds__(256) void gather_cvt(
    const float* __restrict__ x, const int* __restrict__ wi,
    unsigned short* __restrict__ xg)
{
    int idx = blockIdx.x * 256 + threadIdx.x;   // over S*160 (exact)
    int s  = idx / 160;
    int c8 = (idx - s * 160) * 8;
    const float* src = x + (size_t)wi[s] * C_DIM + c8;
    f32x4 v0 = *(const f32x4*)src;
    f32x4 v1 = *(const f32x4*)(src + 4);
    u16x8 o;
    o[0]=f2bf(v0[0]); o[1]=f2bf(v0[1]); o[2]=f2bf(v0[2]); o[3]=f2bf(v0[3]);
    o[4]=f2bf(v1[0]); o[5]=f2bf(v1[1]); o[6]=f2bf(v1[2]); o[7]=f2bf(v1[3]);
    *(u16x8*)&xg[(size_t)s * C_DIM + c8] = o;
}

// ---------------------------------------------------------------------------
// Tiled bf16 MFMA GEMM, global_load_lds staging + XOR-swizzled LDS.
// (unchanged from R1 — verified 862 TF / 0 bank conflicts)
// ---------------------------------------------------------------------------
#define TM 128
#define TN 128
#define BK 64

template<bool OUTF32>
__global__ __launch_bounds__(256) void gemm_mfma(
    const unsigned short* __restrict__ A,   // [M][K] bf16
    const unsigned short* __restrict__ BT,  // [N][K] bf16
    void* __restrict__ Cp,                  // [M][N] fp32 or bf16
    int N, int K)
{
    __shared__ __align__(16) unsigned short As[TM * BK];
    __shared__ __align__(16) unsigned short Bs[TN * BK];

    const int m0   = blockIdx.x * TM;
    const int n0   = blockIdx.y * TN;
    const int tid  = threadIdx.x;
    const int lane = tid & 63;
    const int wv   = tid >> 6;
    const int wm   = (wv >> 1) * 64;
    const int wn   = (wv & 1) * 64;
    const int lrow = lane & 15;
    const int quad = lane >> 4;

    int r_[4], csw[4];
#pragma unroll
    for (int c = 0; c < 4; c++) {
        int ch = (wv * 4 + c) * 64 + lane;
        r_[c]  = ch >> 3;                          // 0..127
        csw[c] = ((ch & 7) ^ (r_[c] & 7)) << 3;    // inverse-swizzled col8
    }

    int aoff[4], asw[4], boff[4], bsw[4];
#pragma unroll
    for (int t = 0; t < 4; t++) {
        int ra = wm + t * 16 + lrow;
        aoff[t] = ra << 7;  asw[t] = (ra & 7) << 4;
        int rb = wn + t * 16 + lrow;
        boff[t] = rb << 7;  bsw[t] = (rb & 7) << 4;
    }

    f32x4 acc[4][4];
#pragma unroll
    for (int i = 0; i < 4; i++)
#pragma unroll
        for (int j = 0; j < 4; j++)
            acc[i][j] = (f32x4){0.f, 0.f, 0.f, 0.f};

    for (int kt = 0; kt < K; kt += BK) {
#pragma unroll
        for (int c = 0; c < 4; c++)
            gload_lds16(A + (size_t)(m0 + r_[c]) * K + kt + csw[c],
                        As + (wv * 4 + c) * 512);
#pragma unroll
        for (int c = 0; c < 4; c++)
            gload_lds16(BT + (size_t)(n0 + r_[c]) * K + kt + csw[c],
                        Bs + (wv * 4 + c) * 512);
        __syncthreads();

#pragma unroll
        for (int ks = 0; ks < BK; ks += 32) {
            const int cb = (ks << 1) + (quad << 4);
            bf16x8 af[4], bfr[4];
#pragma unroll
            for (int mt = 0; mt < 4; mt++)
                af[mt] = *(const bf16x8*)((const char*)As +
                                          aoff[mt] + (cb ^ asw[mt]));
#pragma unroll
            for (int nt = 0; nt < 4; nt++)
                bfr[nt] = *(const bf16x8*)((const char*)Bs +
                                           boff[nt] + (cb ^ bsw[nt]));
#pragma unroll
            for (int mt = 0; mt < 4; mt++)
#pragma unroll
                for (int nt = 0; nt < 4; nt++)
                    acc[mt][nt] = __builtin_amdgcn_mfma_f32_16x16x32_bf16(
                        af[mt], bfr[nt], acc[mt][nt], 0, 0, 0);
        }
        __syncthreads();
    }

#pragma unroll
    for (int mt = 0; mt < 4; mt++)
#pragma unroll
        for (int nt = 0; nt < 4; nt++)
#pragma unroll
            for (int r = 0; r < 4; r++) {
                int row = m0 + wm + mt * 16 + quad * 4 + r;
                int col = n0 + wn + nt * 16 + lrow;
                if (OUTF32)
                    ((float*)Cp)[(size_t)row * N + col] = acc[mt][nt][r];
                else
                    ((unsigned short*)Cp)[(size_t)row * N + col] =
                        f2bf(acc[mt][nt][r]);
            }
}

// ---------------------------------------------------------------------------
// Fused RoPE + block attention, one WAVE per (block b, head h). No LDS.
//
// Conventions (identical to the verified gemm_mfma above):
//   mfma_f32_16x16x32_bf16(Afrag, Bfrag, C):
//     Afrag: lane supplies A[lane&15][ (lane>>4)*8 + e ]
//     Bfrag: lane supplies B[lane&15][ (lane>>4)*8 + e ]
//     C    : lane holds    C[(lane>>4)*4 + r][ lane&15 ]  = sum_k A[i][k]B[j][k]
//
// QK^T with SWAPPED operands: mfma(K', Q') -> lane holds S[q=lane&15][k=quad*4+r]
//   => the whole score row for q-row (lane&15) lives in 4 regs x 4 quads:
//      softmax = 4 in-reg ops + shfl_xor(16,32). All 64 lanes active.
// RoPE is fused into the fragment build (q' = q*cos+k*sin, k' = k*cos-q*sin):
//   same (row, d-chunk) slices feed both fragments -> rope_kernel deleted.
// PV: mfma(V^T, P) -> lane holds O[q=lane&15][d0+quad*4+r] -> 8B stores.
//   P fragment comes from 8 __shfl; V^T fragment from 40 scalar u16 loads
//   (lanes 0..15 read consecutive d -> 32B-coalesced segments, L2-resident).
// P kept UNNORMALIZED in bf16 (e<=1); 1/sum applied in f32 at the store.
// ---------------------------------------------------------------------------
__global__ __launch_bounds__(256) void attn_fused(
    const unsigned short* __restrict__ qkv,   // raw GEMM1 output [S][3840]
    const float* __restrict__ cosp,
    const float* __restrict__ sinp,
    const int* __restrict__ wi,
    unsigned short* __restrict__ y)           // [S][1280] bf16, un-permuted
{
    const int wave = threadIdx.x >> 6;
    const int lane = threadIdx.x & 63;
    const int b    = blockIdx.y;
    const int h    = blockIdx.x * 4 + wave;   // 4 adjacent heads per WG
    const int j16  = lane & 15;
    const int quad = lane >> 4;

    const int    srow = b * BLK + j16;            // windowed-order token row
    const int    crow = wi[srow];                 // rope source row == output row
    const size_t qoff = (size_t)srow * C3_DIM + h * D_DIM;

    // ---- V^T fragments, issued first (T14: hide latency under rope/QK) ----
    // vraw[t]: lane supplies V[quad*8+e][t*16 + j16]; quads 2,3 are the k>=16
    // zero-pad of the K=32 MFMA.
    const unsigned short* vbase =
        qkv + (size_t)b * BLK * C3_DIM + 2 * C_DIM + h * D_DIM + j16;
    u16x8 vraw[5];
#pragma unroll
    for (int t = 0; t < 5; t++) {
#pragma unroll
        for (int e = 0; e < 8; e++) {
            int kks = (quad < 2) ? (quad * 8 + e) : e;   // safe row for pads
            unsigned short rv = vbase[(size_t)kks * C3_DIM + t * 16];
            vraw[t][e] = (quad < 2) ? rv : (unsigned short)0;
        }
    }

    // ---- Q/K fragments with fused RoPE ----
    const unsigned short* qrow = qkv + qoff;
    const float* cr = cosp + (size_t)crow * D_DIM;
    const float* sr = sinp + (size_t)crow * D_DIM;
    bf16x8 qf[3], kf[3];
#pragma unroll
    for (int s = 0; s < 3; s++) {
        int d = 32 * s + quad * 8;
        bool valid = (d < D_DIM);                 // s==2, quad>=2 is k-pad
        int dc = valid ? d : 0;
        u16x8 qv = *(const u16x8*)(qrow + dc);
        u16x8 kv = *(const u16x8*)(qrow + C_DIM + dc);
        f32x4 c0 = *(const f32x4*)(cr + dc);
        f32x4 c1 = *(const f32x4*)(cr + dc + 4);
        f32x4 s0 = *(const f32x4*)(sr + dc);
        f32x4 s1 = *(const f32x4*)(sr + dc + 4);
        u16x8 qo, ko;
#pragma unroll
        for (int j = 0; j < 8; j++) {
            float cw = (j < 4) ? c0[j] : c1[j - 4];
            float sw = (j < 4) ? s0[j] : s1[j - 4];
            float q = bf2f(qv[j]), k = bf2f(kv[j]);
            qo[j] = valid ? f2bf(q * cw + k * sw) : (unsigned short)0;
            ko[j] = valid ? f2bf(k * cw - q * sw) : (unsigned short)0;
        }
        qf[s] = __builtin_bit_cast(bf16x8, qo);
        kf[s] = __builtin_bit_cast(bf16x8, ko);
    }

    // ---- scores: S[q=lane&15][k=quad*4+r] (swapped-operand QK^T) ----
    f32x4 sacc = (f32x4){0.f, 0.f, 0.f, 0.f};
#pragma unroll
    for (int s = 0; s < 3; s++)
        sacc = __builtin_amdgcn_mfma_f32_16x16x32_bf16(kf[s], qf[s], sacc, 0, 0, 0);

    // ---- softmax over k (4 in-reg + cross-quad shfl_xor) ----
    const float scale = 0.11180339887498948f;     // 1/sqrt(80)
    float sc[4];
#pragma unroll
    for (int r = 0; r < 4; r++) sc[r] = sacc[r] * scale;
    float m = fmaxf(fmaxf(sc[0], sc[1]), fmaxf(sc[2], sc[3]));
    m = fmaxf(m, __shfl_xor(m, 16));
    m = fmaxf(m, __shfl_xor(m, 32));
    float e[4], sum = 0.f;
#pragma unroll
    for (int r = 0; r < 4; r++) { e[r] = __expf(sc[r] - m); sum += e[r]; }
    sum += __shfl_xor(sum, 16);
    sum += __shfl_xor(sum, 32);
    float inv = 1.f / sum;

    // ---- P fragment for PV (B-operand): lane needs P[j16][quad*8+e] ----
    // kk = quad*8+e lives at lane (kk>>2)*16 + j16, reg kk&3.
    int sl = quad * 32 + j16;                     // valid for quad<2
    float pv0[4], pv1[4];
#pragma unroll
    for (int r = 0; r < 4; r++) pv0[r] = __shfl(e[r], sl & 63);
#pragma unroll
    for (int r = 0; r < 4; r++) pv1[r] = __shfl(e[r], (sl + 16) & 63);
    u16x8 pf;
#pragma unroll
    for (int r = 0; r < 4; r++) {
        pf[r]     = (quad < 2) ? f2bf(pv0[r]) : (unsigned short)0;
        pf[r + 4] = (quad < 2) ? f2bf(pv1[r]) : (unsigned short)0;
    }
    bf16x8 pfrag = __builtin_bit_cast(bf16x8, pf);

    // ---- PV + normalize + scatter-store: O[j16][t*16+quad*4+r] ----
    unsigned short* yrow = y + (size_t)crow * C_DIM + h * D_DIM + quad * 4;
#pragma unroll
    for (int t = 0; t < 5; t++) {
        f32x4 o = __builtin_amdgcn_mfma_f32_16x16x32_bf16(
            __builtin_bit_cast(bf16x8, vraw[t]), pfrag,
            (f32x4){0.f, 0.f, 0.f, 0.f}, 0, 0, 0);
        u16x4 ov;
#pragma unroll
        for (int r = 0; r < 4; r++) ov[r] = f2bf(o[r] * inv);
        *(u16x4*)(yrow + t * 16) = ov;
    }
}

extern "C" void kernel_launch(void* const* d_in, const int* in_sizes, int n_in,
                              void* d_out, int out_size, void* d_ws, size_t ws_size,
                              hipStream_t stream)
{
    const float* x     = (const float*)d_in[0];
    const float* cosp  = (const float*)d_in[1];
    const float* sinp  = (const float*)d_in[2];
    const float* Wqkv  = (const float*)d_in[3];
    const float* Wproj = (const float*)d_in[4];
    const int*   wi    = (const int*)d_in[5];

    // workspace layout (bytes):
    //   qkv    @ 0          : S*3840*2    = 125,829,120
    //   yun    @ 125829120  : S*1280*2    =  41,943,040
    //   wqkvT  @ 167772160  : 3840*1280*2 =   9,830,400   (bf16 [N][K])
    //   wprojT @ 177602560  : 1280*1280*2 =   3,276,800   (bf16 [N][K])
    //   xg     @ 180879360  : S*1280*2    =  41,943,040   (bf16 gathered x)
    char* ws = (char*)d_ws;
    unsigned short* qkv    = (unsigned short*)ws;
    unsigned short* yun    = (unsigned short*)(ws + 125829120ull);
    unsigned short* wqkvT  = (unsigned short*)(ws + 167772160ull);
    unsigned short* wprojT = (unsigned short*)(ws + 177602560ull);
    unsigned short* xg     = (unsigned short*)(ws + 180879360ull);

    // 0) weight prep: fp32 [K][N] -> bf16 [N][K]
    transpose_cvt<<<dim3(C3_DIM / 32, C_DIM / 32), 256, 0, stream>>>(
        Wqkv, wqkvT, C_DIM, C3_DIM);
    transpose_cvt<<<dim3(C_DIM / 32, C_DIM / 32), 256, 0, stream>>>(
        Wproj, wprojT, C_DIM, C_DIM);

    // 0b) gather + cvt prepass: xg[s] = bf16(x[wi[s]])
    gather_cvt<<<S_TOK * 160 / 256, 256, 0, stream>>>(x, wi, xg);

    // 1) qkv = xg @ W_qkv   (bf16 out to workspace, raw — rope fused in attn)
    gemm_mfma<false><<<dim3(S_TOK / TM, C3_DIM / TN), 256, 0, stream>>>(
        xg, wqkvT, qkv, C3_DIM, C_DIM);

    // 2) fused rope + block attention; scatter rows to un-permuted order
    attn_fused<<<dim3(H_DIM / 4, S_TOK / BLK), 256, 0, stream>>>(
        qkv, cosp, sinp, wi, yun);

    // 3) out = y @ W_proj -> fp32 d_out
    gemm_mfma<true><<<dim3(S_TOK / TM, C_DIM / TN), 256, 0, stream>>>(
        yun, wprojT, d_out, C_DIM, C_DIM);
}

// Round 3
// 476.814 us; speedup vs baseline: 1.1837x; 1.0506x over previous
//
#include <hip/hip_runtime.h>
#include <hip/hip_bf16.h>

// Problem constants (fixed by setup_inputs):
//   B=1, T=16384 -> S=16384, C=1280, H=16, D=80, 3C=3840, block=16, nb=1024
// Inputs FP32, output FP32. Workspace budget 222,822,400 B.
#define S_TOK   16384
#define C_DIM   1280
#define C3_DIM  3840
#define H_DIM   16
#define D_DIM   80
#define BLK     16
#define PLANE_ELEMS ((size_t)S_TOK * C_DIM)   // one of Q/K/V planes, elements

using u16x8  = __attribute__((ext_vector_type(8))) unsigned short;
using u16x4  = __attribute__((ext_vector_type(4))) unsigned short;
using bf16x8 = __attribute__((ext_vector_type(8))) __bf16;
using f32x4  = __attribute__((ext_vector_type(4))) float;

__device__ __forceinline__ unsigned short f2bf(float f) {
    return __bfloat16_as_ushort(__float2bfloat16(f));
}
__device__ __forceinline__ float bf2f(unsigned short u) {
    unsigned int x = (unsigned int)u << 16;
    return __builtin_bit_cast(float, x);
}
__device__ __forceinline__ void gload_lds16(const unsigned short* g, unsigned short* l) {
    __builtin_amdgcn_global_load_lds(
        (const __attribute__((address_space(1))) void*)g,
        (__attribute__((address_space(3))) void*)l, 16, 0, 0);
}

// ---------------------------------------------------------------------------
// One-shot weight prep: fp32 W[K][N] -> bf16 W^T[N][K], LDS-tiled.
// ---------------------------------------------------------------------------
__global__ __launch_bounds__(256) void transpose_cvt(
    const float* __restrict__ W, unsigned short* __restrict__ WT, int K, int N)
{
    __shared__ float tile[32][33];
    const int n0 = blockIdx.x * 32, k0 = blockIdx.y * 32;
    const int tx = threadIdx.x & 31, ty = threadIdx.x >> 5;   // 32x8
#pragma unroll
    for (int i = ty; i < 32; i += 8)
        tile[i][tx] = W[(size_t)(k0 + i) * N + n0 + tx];
    __syncthreads();
#pragma unroll
    for (int i = ty; i < 32; i += 8)
        WT[(size_t)(n0 + i) * K + k0 + tx] = f2bf(tile[tx][i]);
}

// ---------------------------------------------------------------------------
// Prepass: xg[s][:] = bf16(x[wi[s]][:]).  (enables global_load_lds in GEMM1)
// ---------------------------------------------------------------------------
__global__ __launch_bounds__(256) void gather_cvt(
    const float* __restrict__ x, const int* __restrict__ wi,
    unsigned short* __restrict__ xg)
{
    int idx = blockIdx.x * 256 + threadIdx.x;   // over S*160 (exact)
    int s  = idx / 160;
    int c8 = (idx - s * 160) * 8;
    const float* src = x + (size_t)wi[s] * C_DIM + c8;
    f32x4 v0 = *(const f32x4*)src;
    f32x4 v1 = *(const f32x4*)(src + 4);
    u16x8 o;
    o[0]=f2bf(v0[0]); o[1]=f2bf(v0[1]); o[2]=f2bf(v0[2]); o[3]=f2bf(v0[3]);
    o[4]=f2bf(v1[0]); o[5]=f2bf(v1[1]); o[6]=f2bf(v1[2]); o[7]=f2bf(v1[3]);
    *(u16x8*)&xg[(size_t)s * C_DIM + c8] = o;
}

// ---------------------------------------------------------------------------
// Tiled bf16 MFMA GEMM, global_load_lds staging + XOR-swizzled LDS.
// (hot loop unchanged from R1/R2 — verified 862 TF / 0 bank conflicts)
//
// Epilogue modes:
//   OUTMODE 0: fp32 [M][N]
//   OUTMODE 1: bf16 [M][N]
//   OUTMODE 2: bf16 PLANES [which][h][s][d] — for GEMM1. Every 16-col block
//     lies within one (which, head) since 1280 % 16 == 0 and 80 % 16 == 0,
//     so the remap is uniform per-nt index math; the 16-lane 32-B store
//     contiguity is preserved exactly. Gives attention 2560-B contiguous
//     per-(b,h) Q/K/V regions instead of 7680-B-strided rows.
// ---------------------------------------------------------------------------
#define TM 128
#define TN 128
#define BK 64

template<int OUTMODE>
__global__ __launch_bounds__(256) void gemm_mfma(
    const unsigned short* __restrict__ A,   // [M][K] bf16
    const unsigned short* __restrict__ BT,  // [N][K] bf16
    void* __restrict__ Cp,                  // see OUTMODE
    int N, int K)
{
    __shared__ __align__(16) unsigned short As[TM * BK];
    __shared__ __align__(16) unsigned short Bs[TN * BK];

    const int m0   = blockIdx.x * TM;
    const int n0   = blockIdx.y * TN;
    const int tid  = threadIdx.x;
    const int lane = tid & 63;
    const int wv   = tid >> 6;
    const int wm   = (wv >> 1) * 64;
    const int wn   = (wv & 1) * 64;
    const int lrow = lane & 15;
    const int quad = lane >> 4;

    int r_[4], csw[4];
#pragma unroll
    for (int c = 0; c < 4; c++) {
        int ch = (wv * 4 + c) * 64 + lane;
        r_[c]  = ch >> 3;                          // 0..127
        csw[c] = ((ch & 7) ^ (r_[c] & 7)) << 3;    // inverse-swizzled col8
    }

    int aoff[4], asw[4], boff[4], bsw[4];
#pragma unroll
    for (int t = 0; t < 4; t++) {
        int ra = wm + t * 16 + lrow;
        aoff[t] = ra << 7;  asw[t] = (ra & 7) << 4;
        int rb = wn + t * 16 + lrow;
        boff[t] = rb << 7;  bsw[t] = (rb & 7) << 4;
    }

    f32x4 acc[4][4];
#pragma unroll
    for (int i = 0; i < 4; i++)
#pragma unroll
        for (int j = 0; j < 4; j++)
            acc[i][j] = (f32x4){0.f, 0.f, 0.f, 0.f};

    for (int kt = 0; kt < K; kt += BK) {
#pragma unroll
        for (int c = 0; c < 4; c++)
            gload_lds16(A + (size_t)(m0 + r_[c]) * K + kt + csw[c],
                        As + (wv * 4 + c) * 512);
#pragma unroll
        for (int c = 0; c < 4; c++)
            gload_lds16(BT + (size_t)(n0 + r_[c]) * K + kt + csw[c],
                        Bs + (wv * 4 + c) * 512);
        __syncthreads();

#pragma unroll
        for (int ks = 0; ks < BK; ks += 32) {
            const int cb = (ks << 1) + (quad << 4);
            bf16x8 af[4], bfr[4];
#pragma unroll
            for (int mt = 0; mt < 4; mt++)
                af[mt] = *(const bf16x8*)((const char*)As +
                                          aoff[mt] + (cb ^ asw[mt]));
#pragma unroll
            for (int nt = 0; nt < 4; nt++)
                bfr[nt] = *(const bf16x8*)((const char*)Bs +
                                           boff[nt] + (cb ^ bsw[nt]));
#pragma unroll
            for (int mt = 0; mt < 4; mt++)
#pragma unroll
                for (int nt = 0; nt < 4; nt++)
                    acc[mt][nt] = __builtin_amdgcn_mfma_f32_16x16x32_bf16(
                        af[mt], bfr[nt], acc[mt][nt], 0, 0, 0);
        }
        __syncthreads();
    }

    // epilogue: D row = quad*4 + r, col = lane&15  (HW-verified C/D layout)
#pragma unroll
    for (int nt = 0; nt < 4; nt++) {
        const int cb = n0 + wn + nt * 16;          // uniform per nt
        unsigned short* pb = nullptr;
        if (OUTMODE == 2) {
            int which = cb / C_DIM;
            int hc    = cb - which * C_DIM;
            int h     = hc / D_DIM;
            int d0    = hc - h * D_DIM;
            pb = (unsigned short*)Cp + (size_t)which * PLANE_ELEMS
               + (size_t)h * S_TOK * D_DIM + d0 + lrow;
        }
#pragma unroll
        for (int mt = 0; mt < 4; mt++)
#pragma unroll
            for (int r = 0; r < 4; r++) {
                int row = m0 + wm + mt * 16 + quad * 4 + r;
                if (OUTMODE == 0)
                    ((float*)Cp)[(size_t)row * N + cb + lrow] = acc[mt][nt][r];
                else if (OUTMODE == 1)
                    ((unsigned short*)Cp)[(size_t)row * N + cb + lrow] =
                        f2bf(acc[mt][nt][r]);
                else
                    pb[(size_t)row * D_DIM] = f2bf(acc[mt][nt][r]);
            }
    }
}

// ---------------------------------------------------------------------------
// Fused RoPE + block attention, one WAVE per (block b, head h). No LDS.
// Reads Q/K/V from PLANES [which][h][s][d]: per-(b,h) regions are 2560 B
// contiguous -> all fragment loads are L2-line-local (the R2 version read
// rows strided 7680 B over a 120-KB footprint; theory: that scatter was the
// ~220 us cost).
//
// mfma conventions (same as verified gemm): A/B frag lane -> [lane&15][quad*8+e];
// C: lane holds C[quad*4+r][lane&15].
// QK^T swapped: mfma(K',Q') -> S[q=lane&15][k=quad*4+r]; softmax = 4 in-reg
// ops + shfl_xor(16,32). RoPE fused into fragment build. PV: mfma(V^T, P).
// P unnormalized bf16 (e<=1); 1/sum applied fp32 at store.
// ---------------------------------------------------------------------------
__global__ __launch_bounds__(256) void attn_fused(
    const unsigned short* __restrict__ planes,  // [3][H][S][D] bf16
    const float* __restrict__ cosp,
    const float* __restrict__ sinp,
    const int* __restrict__ wi,
    unsigned short* __restrict__ y)             // [S][1280] bf16, un-permuted
{
    const int wave = threadIdx.x >> 6;
    const int lane = threadIdx.x & 63;
    const int b    = blockIdx.y;
    const int h    = blockIdx.x * 4 + wave;   // 4 adjacent heads per WG
    const int j16  = lane & 15;
    const int quad = lane >> 4;

    const int srow = b * BLK + j16;               // windowed-order token row
    const int crow = wi[srow];                    // rope source row == output row

    // ---- V^T fragments, issued first (hide latency under rope/QK) ----
    // vraw[t][e] = V[kks][t*16 + j16], kks = quad*8+e (quads 2,3 zero-pad).
    const unsigned short* Vb = planes + 2 * PLANE_ELEMS
        + ((size_t)h * S_TOK + b * BLK) * D_DIM + j16;
    u16x8 vraw[5];
#pragma unroll
    for (int t = 0; t < 5; t++) {
#pragma unroll
        for (int e = 0; e < 8; e++) {
            int kks = (quad < 2) ? (quad * 8 + e) : e;   // safe row for pads
            unsigned short rv = Vb[(size_t)kks * D_DIM + t * 16];
            vraw[t][e] = (quad < 2) ? rv : (unsigned short)0;
        }
    }

    // ---- Q/K fragments with fused RoPE ----
    const unsigned short* Qr = planes + ((size_t)h * S_TOK + srow) * D_DIM;
    const unsigned short* Kr = Qr + PLANE_ELEMS;
    const float* cr = cosp + (size_t)crow * D_DIM;
    const float* sr = sinp + (size_t)crow * D_DIM;
    bf16x8 qf[3], kf[3];
#pragma unroll
    for (int s = 0; s < 3; s++) {
        int d = 32 * s + quad * 8;
        bool valid = (d < D_DIM);                 // s==2, quad>=2 is k-pad
        int dc = valid ? d : 0;
        u16x8 qv = *(const u16x8*)(Qr + dc);
        u16x8 kv = *(const u16x8*)(Kr + dc);
        f32x4 c0 = *(const f32x4*)(cr + dc);
        f32x4 c1 = *(const f32x4*)(cr + dc + 4);
        f32x4 s0 = *(const f32x4*)(sr + dc);
        f32x4 s1 = *(const f32x4*)(sr + dc + 4);
        u16x8 qo, ko;
#pragma unroll
        for (int j = 0; j < 8; j++) {
            float cw = (j < 4) ? c0[j] : c1[j - 4];
            float sw = (j < 4) ? s0[j] : s1[j - 4];
            float q = bf2f(qv[j]), k = bf2f(kv[j]);
            qo[j] = valid ? f2bf(q * cw + k * sw) : (unsigned short)0;
            ko[j] = valid ? f2bf(k * cw - q * sw) : (unsigned short)0;
        }
        qf[s] = __builtin_bit_cast(bf16x8, qo);
        kf[s] = __builtin_bit_cast(bf16x8, ko);
    }

    // ---- scores: S[q=lane&15][k=quad*4+r] (swapped-operand QK^T) ----
    f32x4 sacc = (f32x4){0.f, 0.f, 0.f, 0.f};
#pragma unroll
    for (int s = 0; s < 3; s++)
        sacc = __builtin_amdgcn_mfma_f32_16x16x32_bf16(kf[s], qf[s], sacc, 0, 0, 0);

    // ---- softmax over k (4 in-reg + cross-quad shfl_xor) ----
    const float scale = 0.11180339887498948f;     // 1/sqrt(80)
    float sc[4];
#pragma unroll
    for (int r = 0; r < 4; r++) sc[r] = sacc[r] * scale;
    float m = fmaxf(fmaxf(sc[0], sc[1]), fmaxf(sc[2], sc[3]));
    m = fmaxf(m, __shfl_xor(m, 16));
    m = fmaxf(m, __shfl_xor(m, 32));
    float e[4], sum = 0.f;
#pragma unroll
    for (int r = 0; r < 4; r++) { e[r] = __expf(sc[r] - m); sum += e[r]; }
    sum += __shfl_xor(sum, 16);
    sum += __shfl_xor(sum, 32);
    float inv = 1.f / sum;

    // ---- P fragment for PV (B-operand): lane needs P[j16][quad*8+e] ----
    int sl = quad * 32 + j16;                     // valid for quad<2
    float pv0[4], pv1[4];
#pragma unroll
    for (int r = 0; r < 4; r++) pv0[r] = __shfl(e[r], sl & 63);
#pragma unroll
    for (int r = 0; r < 4; r++) pv1[r] = __shfl(e[r], (sl + 16) & 63);
    u16x8 pf;
#pragma unroll
    for (int r = 0; r < 4; r++) {
        pf[r]     = (quad < 2) ? f2bf(pv0[r]) : (unsigned short)0;
        pf[r + 4] = (quad < 2) ? f2bf(pv1[r]) : (unsigned short)0;
    }
    bf16x8 pfrag = __builtin_bit_cast(bf16x8, pf);

    // ---- PV + normalize + scatter-store: O[j16][t*16+quad*4+r] ----
    unsigned short* yrow = y + (size_t)crow * C_DIM + h * D_DIM + quad * 4;
#pragma unroll
    for (int t = 0; t < 5; t++) {
        f32x4 o = __builtin_amdgcn_mfma_f32_16x16x32_bf16(
            __builtin_bit_cast(bf16x8, vraw[t]), pfrag,
            (f32x4){0.f, 0.f, 0.f, 0.f}, 0, 0, 0);
        u16x4 ov;
#pragma unroll
        for (int r = 0; r < 4; r++) ov[r] = f2bf(o[r] * inv);
        *(u16x4*)(yrow + t * 16) = ov;
    }
}

extern "C" void kernel_launch(void* const* d_in, const int* in_sizes, int n_in,
                              void* d_out, int out_size, void* d_ws, size_t ws_size,
                              hipStream_t stream)
{
    const float* x     = (const float*)d_in[0];
    const float* cosp  = (const float*)d_in[1];
    const float* sinp  = (const float*)d_in[2];
    const float* Wqkv  = (const float*)d_in[3];
    const float* Wproj = (const float*)d_in[4];
    const int*   wi    = (const int*)d_in[5];

    // workspace layout (bytes):
    //   qkv planes @ 0        : S*3840*2    = 125,829,120  ([3][H][S][D])
    //   yun    @ 125829120    : S*1280*2    =  41,943,040
    //   wqkvT  @ 167772160    : 3840*1280*2 =   9,830,400   (bf16 [N][K])
    //   wprojT @ 177602560    : 1280*1280*2 =   3,276,800   (bf16 [N][K])
    //   xg     @ 180879360    : S*1280*2    =  41,943,040   (bf16 gathered x)
    char* ws = (char*)d_ws;
    unsigned short* planes = (unsigned short*)ws;
    unsigned short* yun    = (unsigned short*)(ws + 125829120ull);
    unsigned short* wqkvT  = (unsigned short*)(ws + 167772160ull);
    unsigned short* wprojT = (unsigned short*)(ws + 177602560ull);
    unsigned short* xg     = (unsigned short*)(ws + 180879360ull);

    // 0) weight prep: fp32 [K][N] -> bf16 [N][K]
    transpose_cvt<<<dim3(C3_DIM / 32, C_DIM / 32), 256, 0, stream>>>(
        Wqkv, wqkvT, C_DIM, C3_DIM);
    transpose_cvt<<<dim3(C_DIM / 32, C_DIM / 32), 256, 0, stream>>>(
        Wproj, wprojT, C_DIM, C_DIM);

    // 0b) gather + cvt prepass: xg[s] = bf16(x[wi[s]])
    gather_cvt<<<S_TOK * 160 / 256, 256, 0, stream>>>(x, wi, xg);

    // 1) qkv = xg @ W_qkv, written as [3][H][S][D] planes (rope fused in attn)
    gemm_mfma<2><<<dim3(S_TOK / TM, C3_DIM / TN), 256, 0, stream>>>(
        xg, wqkvT, planes, C3_DIM, C_DIM);

    // 2) fused rope + block attention; scatter rows to un-permuted order
    attn_fused<<<dim3(H_DIM / 4, S_TOK / BLK), 256, 0, stream>>>(
        planes, cosp, sinp, wi, yun);

    // 3) out = y @ W_proj -> fp32 d_out
    gemm_mfma<0><<<dim3(S_TOK / TM, C_DIM / TN), 256, 0, stream>>>(
        yun, wprojT, d_out, C_DIM, C_DIM);
}